// Round 1
// baseline (141.251 us; speedup 1.0000x reference)
//
#include <hip/hip_runtime.h>
#include <stdint.h>

// VQ-VAE vector quantizer — fp32, NCHW input [64,64,32,32], emb [1024,64].
// r18: swapped-operand MFMA (D[code][point]; A/B share lane mapping so the
// r8/r11-verified fragments are reused as-is). Each lane owns one point's
// scores per tile -> per-lane register candidate lists (u64 shift/or push),
// no ballots / col==0 serial extraction; sweep-1 reduce is 2 shuffles.
// acc init = float4 load of C[k..k+3] * -0.5 (per-row C). vq_fin merged into
// the last vq_main block (threadfence+atomic counter, identical add order).
// vq_init widened to 16x64 for 4x parallelism on the serialized prologue.
constexpr int KCODES = 1024;
constexpr int DDIM   = 64;
constexpr int HW     = 1024;
constexpr int NPTS   = 65536;
constexpr int PPB    = 64;            // points per block
constexpr int NBLK   = NPTS / PPB;    // 1024

constexpr int OUT_Q    = 0;
constexpr int OUT_IDX  = 4194304;
constexpr int OUT_LOSS = 4259840;
constexpr int OUT_NLL  = 4259841;

// ws 32-bit-unit offsets
constexpr int WS_MAXC  = 0;       // 16 f  : per-init-block max C
constexpr int WS_C     = 16;      // 1024 f: exact np C_k
constexpr int WS_E     = 2048;    // 32768 u32: SWIZZLED bf16-E (64 chunks x 2KB)
constexpr int WS_PART  = 34816;   // 1024 f: per-block loss partials
constexpr int WS_CTR   = 35840;   // 1 u32 : done-counter for fin merge

typedef __attribute__((ext_vector_type(8))) short short8v;
typedef __attribute__((ext_vector_type(4))) float float4v;

__device__ __forceinline__ uint16_t f2bf(float f) {   // RNE fp32->bf16
    uint32_t u = __float_as_uint(f);
    return (uint16_t)((u + 0x7fffu + ((u >> 16) & 1u)) >> 16);
}
__device__ __forceinline__ uint32_t pack2bf(float a, float b) {
    return (uint32_t)f2bf(a) | ((uint32_t)f2bf(b) << 16);
}

__device__ __forceinline__ float np_pairwise_sumsq64(const float* a) {
    float r[8];
    #pragma unroll
    for (int j = 0; j < 8; ++j) r[j] = __fmul_rn(a[j], a[j]);
    #pragma unroll
    for (int i = 8; i < 64; i += 8)
        #pragma unroll
        for (int j = 0; j < 8; ++j)
            r[j] = __fadd_rn(r[j], __fmul_rn(a[i + j], a[i + j]));
    return __fadd_rn(__fadd_rn(__fadd_rn(r[0], r[1]), __fadd_rn(r[2], r[3])),
                     __fadd_rn(__fadd_rn(r[4], r[5]), __fadd_rn(r[6], r[7])));
}

// 16 blocks x 64 threads: code k = blockIdx*64 + tid. Writes SWIZZLED E.
__global__ __launch_bounds__(64) void vq_init(const float* __restrict__ emb,
                                              float* __restrict__ ws) {
    const int k = blockIdx.x * 64 + threadIdx.x;
    float row[DDIM];
    const float4* src = (const float4*)(emb + (size_t)k * DDIM);
    #pragma unroll
    for (int j = 0; j < 16; ++j) ((float4*)row)[j] = src[j];
    float C = np_pairwise_sumsq64(row);
    ws[WS_C + k] = C;
    {
        const int c = k >> 4, col = k & 15;
        uint32_t* eb = (uint32_t*)ws + WS_E + c * 512;   // chunk base (u32)
        #pragma unroll
        for (int q = 0; q < 4; ++q) {
            uint32_t* d0 = eb + (q * 16 + col) * 4;          // b0 plane
            uint32_t* d1 = eb + 256 + (q * 16 + col) * 4;    // b1 plane
            #pragma unroll
            for (int j = 0; j < 4; ++j) {
                d0[j] = pack2bf(row[q * 8 + 2 * j],      row[q * 8 + 2 * j + 1]);
                d1[j] = pack2bf(row[32 + q * 8 + 2 * j], row[32 + q * 8 + 2 * j + 1]);
            }
        }
    }
    float m = C;
    #pragma unroll
    for (int off = 32; off > 0; off >>= 1) m = fmaxf(m, __shfl_down(m, off, 64));
    if (threadIdx.x == 0) ws[WS_MAXC + blockIdx.x] = m;
    if (k == 0) ((uint32_t*)ws)[WS_CTR] = 0u;
}

__global__ __launch_bounds__(256, 4) void vq_main(
        const float* __restrict__ inp, const float* __restrict__ emb,
        float* __restrict__ ws, float* __restrict__ out)
{
    __shared__ float    sAp[PPB][4];    // pairwise partials (r2j + r2j+1)
    __shared__ float    sA[PPB];
    __shared__ float    sPart[4][PPB];
    __shared__ float    sThr[PPB];
    __shared__ unsigned long long sCandL[16][PPB];  // [wave*4+quad][point]
    __shared__ int      sCntL[16][PPB];
    __shared__ int      sWin[PPB];
    __shared__ float    sred[4];
    __shared__ int      sLast;

    const int tid  = threadIdx.x;
    const int lane = tid & 63;
    const int wave = tid >> 6;          // = code quarter
    const int col  = lane & 15;         // = POINT within 16-group (swapped layout)
    const int quad = lane >> 4;         // = code sub-quad (rows quad*4+r)
    const int base = blockIdx.x * PPB;
    const int b    = base >> 10;
    const int hw0  = base & 1023;

    // ---- prologue: exact-A partials, 4 threads per point (bit-exact tree
    //      split of np pairwise: this thread computes r_{2j}+r_{2j+1}) -------
    {
        const int pp = tid >> 2;            // point
        const int jj = (tid & 3) * 2;       // r-pair base
        const float* xin = inp + (size_t)b * DDIM * HW + (hw0 + pp);
        float r0, r1;
        {
            float v0 = xin[(size_t)jj * HW];
            float v1 = xin[(size_t)(jj + 1) * HW];
            r0 = __fmul_rn(v0, v0);
            r1 = __fmul_rn(v1, v1);
        }
        #pragma unroll
        for (int i = 8; i < 64; i += 8) {
            float v0 = xin[(size_t)(i + jj) * HW];
            float v1 = xin[(size_t)(i + jj + 1) * HW];
            r0 = __fadd_rn(r0, __fmul_rn(v0, v0));
            r1 = __fadd_rn(r1, __fmul_rn(v1, v1));
        }
        sAp[pp][tid & 3] = __fadd_rn(r0, r1);
    }

    // ---- X-fragments for 4 row-groups (unchanged; reused as MFMA B-op) ----
    short8v a[4][2];
    #pragma unroll
    for (int g = 0; g < 4; ++g) {
        const float* xp = inp + (size_t)b * DDIM * HW + (hw0 + g * 16 + col);
        short8v t0, t1;
        #pragma unroll
        for (int j = 0; j < 8; ++j) {
            t0[j] = (short)f2bf(xp[(size_t)(quad * 8 + j) * HW]);
            t1[j] = (short)f2bf(xp[(size_t)(32 + quad * 8 + j) * HW]);
        }
        a[g][0] = t0; a[g][1] = t1;
    }

    // swizzled E: lane reads its 16B at chunk*2048 + plane*1024 + lane*16 —
    // contiguous 1KB per wave-load; lane&15 indexes CODE -> valid A-fragment.
    const char* Eb = (const char*)((const uint32_t*)ws + WS_E);
    const char* Ew = Eb + (size_t)wave * 16 * 2048 + (size_t)lane * 16;
    const float* Cw = ws + WS_C;
    const int k0 = wave * 256;
    const float4v* Cq = (const float4v*)(ws + WS_C + k0);   // 16B-aligned

    // ---- sweep 1: per-point score-max, per-lane (no shuffles in loop) -----
    float gmax[4] = {-3.0e38f, -3.0e38f, -3.0e38f, -3.0e38f};
    {
        short8v pa0 = *(const short8v*)(Ew);
        short8v pa1 = *(const short8v*)(Ew + 1024);
        short8v pb0 = *(const short8v*)(Ew + 2048);
        short8v pb1 = *(const short8v*)(Ew + 3072);
        float4v ca4 = Cq[quad];
        float4v cb4 = Cq[4 + quad];
        #pragma unroll 1
        for (int c2 = 0; c2 < 16; c2 += 2) {
            short8v u0 = pa0, u1 = pa1; float4v uc4 = ca4;
            if (c2 + 2 < 16) {
                const char* er = Ew + (size_t)(c2 + 2) * 2048;
                pa0 = *(const short8v*)(er);
                pa1 = *(const short8v*)(er + 1024);
                ca4 = Cq[(c2 + 2) * 4 + quad];
            }
            {
                float4v ci = {uc4[0] * -0.5f, uc4[1] * -0.5f,
                              uc4[2] * -0.5f, uc4[3] * -0.5f};
                #pragma unroll
                for (int g = 0; g < 4; ++g) {
                    float4v acc = ci;
                    acc = __builtin_amdgcn_mfma_f32_16x16x32_bf16(u0, a[g][0], acc, 0, 0, 0);
                    acc = __builtin_amdgcn_mfma_f32_16x16x32_bf16(u1, a[g][1], acc, 0, 0, 0);
                    gmax[g] = fmaxf(gmax[g],
                                    fmaxf(fmaxf(acc[0], acc[1]), fmaxf(acc[2], acc[3])));
                }
            }
            short8v v0 = pb0, v1 = pb1; float4v vc4 = cb4;
            if (c2 + 3 < 16) {
                const char* er = Ew + (size_t)(c2 + 3) * 2048;
                pb0 = *(const short8v*)(er);
                pb1 = *(const short8v*)(er + 1024);
                cb4 = Cq[(c2 + 3) * 4 + quad];
            }
            {
                float4v ci = {vc4[0] * -0.5f, vc4[1] * -0.5f,
                              vc4[2] * -0.5f, vc4[3] * -0.5f};
                #pragma unroll
                for (int g = 0; g < 4; ++g) {
                    float4v acc = ci;
                    acc = __builtin_amdgcn_mfma_f32_16x16x32_bf16(v0, a[g][0], acc, 0, 0, 0);
                    acc = __builtin_amdgcn_mfma_f32_16x16x32_bf16(v1, a[g][1], acc, 0, 0, 0);
                    gmax[g] = fmaxf(gmax[g],
                                    fmaxf(fmaxf(acc[0], acc[1]), fmaxf(acc[2], acc[3])));
                }
            }
        }
    }
    // cross-quad reduce: 2 shuffles (was a 64-shuffle tree)
    #pragma unroll
    for (int g = 0; g < 4; ++g) {
        float m = gmax[g];
        m = fmaxf(m, __shfl_xor(m, 16, 64));
        m = fmaxf(m, __shfl_xor(m, 32, 64));
        if (quad == 0) sPart[wave][g * 16 + col] = m;
    }
    __syncthreads();

    // ---- per-point threshold (also combine exact-A partials, exact tree) ---
    if (tid < PPB) {
        float A = __fadd_rn(__fadd_rn(sAp[tid][0], sAp[tid][1]),
                            __fadd_rn(sAp[tid][2], sAp[tid][3]));
        sA[tid] = A;
        float gm = fmaxf(fmaxf(sPart[0][tid], sPart[1][tid]),
                         fmaxf(sPart[2][tid], sPart[3][tid]));
        float mc = ws[WS_MAXC];
        #pragma unroll
        for (int j = 1; j < 16; ++j) mc = fmaxf(mc, ws[WS_MAXC + j]);
        sThr[tid] = gm - (0.015625f * sqrtf(A) * sqrtf(mc) + 6e-5f);
    }
    __syncthreads();

    float thrg[4];
    #pragma unroll
    for (int g = 0; g < 4; ++g) thrg[g] = sThr[g * 16 + col];

    // ---- sweep 2: candidates via per-lane u64 register lists ---------------
    unsigned long long lst[4] = {0ull, 0ull, 0ull, 0ull};
    int cnt[4] = {0, 0, 0, 0};
    {
        short8v pa0 = *(const short8v*)(Ew);
        short8v pa1 = *(const short8v*)(Ew + 1024);
        short8v pb0 = *(const short8v*)(Ew + 2048);
        short8v pb1 = *(const short8v*)(Ew + 3072);
        float4v ca4 = Cq[quad];
        float4v cb4 = Cq[4 + quad];
        #pragma unroll 1
        for (int c2 = 0; c2 < 16; c2 += 2) {
            short8v u0 = pa0, u1 = pa1; float4v uc4 = ca4;
            if (c2 + 2 < 16) {
                const char* er = Ew + (size_t)(c2 + 2) * 2048;
                pa0 = *(const short8v*)(er);
                pa1 = *(const short8v*)(er + 1024);
                ca4 = Cq[(c2 + 2) * 4 + quad];
            }
            {
                float4v ci = {uc4[0] * -0.5f, uc4[1] * -0.5f,
                              uc4[2] * -0.5f, uc4[3] * -0.5f};
                const int kb = k0 + c2 * 16 + quad * 4;
                #pragma unroll
                for (int g = 0; g < 4; ++g) {
                    float4v acc = ci;
                    acc = __builtin_amdgcn_mfma_f32_16x16x32_bf16(u0, a[g][0], acc, 0, 0, 0);
                    acc = __builtin_amdgcn_mfma_f32_16x16x32_bf16(u1, a[g][1], acc, 0, 0, 0);
                    float m4 = fmaxf(fmaxf(acc[0], acc[1]), fmaxf(acc[2], acc[3]));
                    if (__any(m4 >= thrg[g])) {
                        #pragma unroll
                        for (int r = 0; r < 4; ++r) {
                            if (acc[r] >= thrg[g]) {
                                if (cnt[g] < 4)
                                    lst[g] |= (unsigned long long)(unsigned)(kb + r)
                                              << (cnt[g] << 4);
                                ++cnt[g];
                            }
                        }
                    }
                }
            }
            short8v v0 = pb0, v1 = pb1; float4v vc4 = cb4;
            if (c2 + 3 < 16) {
                const char* er = Ew + (size_t)(c2 + 3) * 2048;
                pb0 = *(const short8v*)(er);
                pb1 = *(const short8v*)(er + 1024);
                cb4 = Cq[(c2 + 3) * 4 + quad];
            }
            {
                float4v ci = {vc4[0] * -0.5f, vc4[1] * -0.5f,
                              vc4[2] * -0.5f, vc4[3] * -0.5f};
                const int kb = k0 + (c2 + 1) * 16 + quad * 4;
                #pragma unroll
                for (int g = 0; g < 4; ++g) {
                    float4v acc = ci;
                    acc = __builtin_amdgcn_mfma_f32_16x16x32_bf16(v0, a[g][0], acc, 0, 0, 0);
                    acc = __builtin_amdgcn_mfma_f32_16x16x32_bf16(v1, a[g][1], acc, 0, 0, 0);
                    float m4 = fmaxf(fmaxf(acc[0], acc[1]), fmaxf(acc[2], acc[3]));
                    if (__any(m4 >= thrg[g])) {
                        #pragma unroll
                        for (int r = 0; r < 4; ++r) {
                            if (acc[r] >= thrg[g]) {
                                if (cnt[g] < 4)
                                    lst[g] |= (unsigned long long)(unsigned)(kb + r)
                                              << (cnt[g] << 4);
                                ++cnt[g];
                            }
                        }
                    }
                }
            }
        }
    }
    {
        const int wq = wave * 4 + quad;
        #pragma unroll
        for (int g = 0; g < 4; ++g) {
            sCandL[wq][g * 16 + col] = lst[g];
            sCntL[wq][g * 16 + col]  = cnt[g];
        }
    }
    __syncthreads();

    // ---- rescue: exact np-fp32 on candidates -------------------------------
    if (tid < PPB) {
        const int p = tid, n = base + p;
        int tot = 0, cmax = 0;
        #pragma unroll
        for (int wq = 0; wq < 16; ++wq) {
            int c = sCntL[wq][p];
            tot += c;
            cmax = c > cmax ? c : cmax;
        }
        int win;
        if (tot == 1) {
            win = 0;
            #pragma unroll
            for (int wq = 0; wq < 16; ++wq)
                if (sCntL[wq][p]) win = (int)(sCandL[wq][p] & 0xffffu);
        } else {
            const float* xin = inp + (size_t)b * DDIM * HW + (hw0 + p);
            float x[DDIM];
            #pragma unroll
            for (int d = 0; d < DDIM; ++d) x[d] = xin[(size_t)d * HW];
            const float A = sA[p];
            float bd = 3.0e38f; win = KCODES - 1;
            if (cmax <= 4) {
                #pragma unroll 1
                for (int wq = 0; wq < 16; ++wq) {
                    int c = sCntL[wq][p];
                    unsigned long long L = sCandL[wq][p];
                    #pragma unroll 1
                    for (int i = 0; i < c; ++i) {
                        int k = (int)(L & 0xffffu);
                        L >>= 16;
                        float e[DDIM];
                        const float4* e4 = (const float4*)(emb + (size_t)k * DDIM);
                        #pragma unroll
                        for (int j = 0; j < 16; ++j) ((float4*)e)[j] = e4[j];
                        float g = 0.f;
                        #pragma unroll
                        for (int d = 0; d < DDIM; ++d) g = fmaf(x[d], e[d], g);
                        float dd = __fadd_rn(__fsub_rn(A, __fmul_rn(2.0f, g)), Cw[k]);
                        if (dd < bd || (dd == bd && k < win)) { bd = dd; win = k; }
                    }
                }
            } else {                                    // overflow safety
                #pragma unroll 1
                for (int k = 0; k < KCODES; ++k) {
                    float e[DDIM];
                    const float4* e4 = (const float4*)(emb + (size_t)k * DDIM);
                    #pragma unroll
                    for (int j = 0; j < 16; ++j) ((float4*)e)[j] = e4[j];
                    float g = 0.f;
                    #pragma unroll
                    for (int d = 0; d < DDIM; ++d) g = fmaf(x[d], e[d], g);
                    float dd = __fadd_rn(__fsub_rn(A, __fmul_rn(2.0f, g)), Cw[k]);
                    if (dd < bd) { bd = dd; win = k; }
                }
            }
        }
        sWin[p] = win;
        out[OUT_IDX + n] = (float)win;
    }
    __syncthreads();

    // ---- epilogue: quantized NCHW + loss partial (plain store) -------------
    {
        const int pl = tid & 63, qtr = tid >> 6;
        const int win = sWin[pl];
        const int ch0 = qtr * 16;
        float q[16];
        const float4* q4 = (const float4*)(emb + (size_t)win * DDIM + ch0);
        #pragma unroll
        for (int j = 0; j < 4; ++j) ((float4*)q)[j] = q4[j];
        const size_t off = (size_t)b * DDIM * HW + (size_t)ch0 * HW + (hw0 + pl);
        const float* xin2 = inp + off;
        float* orow = out + off;
        float lacc = 0.f;
        #pragma unroll
        for (int j = 0; j < 16; ++j) {
            float xv = xin2[(size_t)j * HW];
            float diff = __fsub_rn(q[j], xv);
            orow[(size_t)j * HW] = __fadd_rn(xv, diff);   // ref's x + (q - x)
            lacc = fmaf(diff, diff, lacc);
        }
        #pragma unroll
        for (int o2 = 32; o2 > 0; o2 >>= 1) lacc += __shfl_down(lacc, o2, 64);
        if (lane == 0) sred[wave] = lacc;
    }
    __syncthreads();

    // ---- fin merged: last block reduces partials (identical add order) -----
    if (tid == 0) {
        ws[WS_PART + blockIdx.x] = sred[0] + sred[1] + sred[2] + sred[3];
        __threadfence();
        unsigned int old = atomicAdd((unsigned int*)ws + WS_CTR, 1u);
        sLast = (old == NBLK - 1) ? 1 : 0;
    }
    __syncthreads();
    if (sLast) {
        __threadfence();
        float s = 0.f;
        #pragma unroll
        for (int j = 0; j < 4; ++j) s += ws[WS_PART + j * 256 + tid];
        #pragma unroll
        for (int off = 32; off > 0; off >>= 1) s += __shfl_down(s, off, 64);
        if ((tid & 63) == 0) sred[tid >> 6] = s;
        __syncthreads();
        if (tid == 0) {
            float L = sred[0] + sred[1] + sred[2] + sred[3];
            out[OUT_LOSS] = L * (1.25f / 4194304.0f);   // (1+CC)*mean over N*D
            out[OUT_NLL]  = 1.0f;
        }
    }
}

extern "C" void kernel_launch(void* const* d_in, const int* in_sizes, int n_in,
                              void* d_out, int out_size, void* d_ws, size_t ws_size,
                              hipStream_t stream) {
    const float* inp = (const float*)d_in[0];
    const float* emb = (const float*)d_in[1];
    float* out = (float*)d_out;
    float* ws  = (float*)d_ws;

    vq_init<<<16, 64, 0, stream>>>(emb, ws);
    vq_main<<<NBLK, 256, 0, stream>>>(inp, emb, ws, out);
}